// Round 4
// baseline (713.175 us; speedup 1.0000x reference)
//
#include <hip/hip_runtime.h>

// RNN_Model: biLSTM (T=300,B=4096,D=39,H1=35,H2=30) + FC(50,40,2)
// Round 9:
//  - revert R8's lgkmcnt-only barrier (regressed ~11us) -> __syncthreads().
//  - reorder loop body: A-frag ds_reads issued first, x stage-write moved
//    between them and the MFMAs (fills the post-barrier LDS-latency bubble
//    with independent VALU; shortens pre-barrier tail). Numerics identical.
//  - sig(a)*tanh(b) merged-rcp form: (e^2b-1)*rcp((1+e^-a)(e^2b+1));
//    10 -> 8 transcendentals per unit-row (~20% less trans issue).
//  fc: R8 software-pipelined version (kept; -17us measured).

#define T_STEPS 300
#define DIN 39
#define H1 35
#define H2 30
#define BATCH 4096
#define FC1N 50
#define FC2N 40

#define AP_STR 104       // halfs per A-panel row (52 dwords; rows 16B-aligned for b128)

typedef _Float16 f16;
typedef _Float16 half8 __attribute__((ext_vector_type(8)));
typedef float floatx4 __attribute__((ext_vector_type(4)));

__device__ __forceinline__ float sigf(float x) {
    return __builtin_amdgcn_rcpf(1.0f + __expf(-x));
}
// sig(a)*tanh(b) with a single rcp: (e^{2b}-1) / ((1+e^{-a})(e^{2b}+1))
__device__ __forceinline__ float sig_tanh(float a, float b) {
    float ea = __expf(-a);
    float E  = __expf(2.0f * b);
    return (E - 1.0f) * __builtin_amdgcn_rcpf((1.0f + ea) * (E + 1.0f));
}

// ---------------- wprep: LSTM weight B-fragments, gate-major ----------------------------
// frag = dir*60 + (layer==0 ? ug*12+g*3+c : 36 + ug*12+g*3+c)
// B cols = units ug*16+0..15 of gate g; K rows: L1 x[0,40)|h1[40,75); L2 h1[0,35)|h2[35,65)
__global__ void wprep_kernel(const float* __restrict__ fw1, const float* __restrict__ bw1,
                             const float* __restrict__ fw2, const float* __restrict__ bw2,
                             f16* __restrict__ bp) {
    int frag = blockIdx.x;        // 0..119
    int lane = threadIdx.x;       // 0..63
    int dir = frag / 60;
    int rem = frag % 60;
    int layer = (rem < 36) ? 0 : 1;
    int r2 = (layer == 0) ? rem : rem - 36;
    int ug = r2 / 12, g = (r2 % 12) / 3, c = r2 % 3;
    int u = ug * 16 + (lane & 15);
    const float* W = (layer == 0) ? (dir ? bw1 : fw1) : (dir ? bw2 : fw2);
    for (int j = 0; j < 8; ++j) {
        int k = c * 32 + (lane >> 4) * 8 + j;
        float v = 0.0f;
        if (layer == 0) {
            if (u < H1) {
                int kr = (k < 39) ? k : ((k >= 40 && k < 75) ? k - 1 : -1);
                if (kr >= 0) v = W[kr * (4 * H1) + g * H1 + u];
            }
        } else {
            if (u < H2 && k < 65) v = W[k * (4 * H2) + g * H2 + u];
        }
        bp[(size_t)frag * 512 + lane * 8 + j] = (f16)v;
    }
}

// ---------------- fcwprep: FC weight B-fragments ----------------------------------------
// f 0..7: fc1 (tile 0..3, chunk 0..1); 8..13: fc2 (tile 0..2); 14..15: out
__global__ void fcwprep_kernel(const float* __restrict__ Wf1, const float* __restrict__ Wf2,
                               const float* __restrict__ Wo, f16* __restrict__ fcp) {
    int f = blockIdx.x;
    int lane = threadIdx.x;
    int lm = lane & 15, oct = lane >> 4;
    for (int j = 0; j < 8; ++j) {
        float v = 0.0f;
        if (f < 8) {
            int tile = f >> 1, chunk = f & 1;
            int n = tile * 16 + lm;
            int kl = chunk * 32 + oct * 8 + j;   // LDS K: fw 0..29 | pad | bw 32..61 | pad
            int krow = (kl < 30) ? kl : ((kl >= 32 && kl < 62) ? kl - 2 : -1);
            if (n < FC1N && krow >= 0) v = Wf1[krow * FC1N + n];
        } else if (f < 14) {
            int g = f - 8, tile = g >> 1, chunk = g & 1;
            int n = tile * 16 + lm;
            int k = chunk * 32 + oct * 8 + j;
            if (n < FC2N && k < FC1N) v = Wf2[k * FC2N + n];
        } else {
            int chunk = f - 14;
            int k = chunk * 32 + oct * 8 + j;
            if (lm < 2 && k < FC2N) v = Wo[k * 2 + lm];
        }
        fcp[(size_t)f * 512 + lane * 8 + j] = (f16)v;
    }
}

// ---------------- fused 2-layer LSTM -----------------------------------------------------
__global__ __launch_bounds__(320, 3) void lstm_fused(
    const float* __restrict__ x, const f16* __restrict__ bp,
    const float* __restrict__ fb1, const float* __restrict__ bb1,
    const float* __restrict__ fb2, const float* __restrict__ bb2,
    f16* __restrict__ h2s)
{
    __shared__ f16 pan1[2][16 * AP_STR];  // L1: x[0,40) | h1[40,75) | 0[75,96)
    __shared__ f16 pan2[2][16 * AP_STR];  // L2: h1[0,35) | h2[35,65) | 0[65,96)

    const int tid = threadIdx.x;
    const int b0  = blockIdx.x * 16;
    const int dir = blockIdx.y;
    const int wv   = tid >> 6;            // 0..4
    const int lane = tid & 63;
    const int lm = lane & 15, oct = lane >> 4;
    const bool isL2 = (wv >= 3);
    const int ug = isL2 ? (wv - 3) : wv;  // unit group within its layer
    const int u  = ug * 16 + lm;          // this lane's unit
    const int Hn = isL2 ? H2 : H1;
    const float* bias = isL2 ? (dir ? bb2 : fb2) : (dir ? bb1 : fb1);
    const int fragbase = dir * 60 + (isL2 ? 36 : 0) + ug * 12;

    // persistent gate-major B-fragments (one layer's set per wave)
    half8 bf[4][3];
    #pragma unroll
    for (int g = 0; g < 4; ++g)
        #pragma unroll
        for (int c = 0; c < 3; ++c)
            bf[g][c] = *(const half8*)(bp + (size_t)(fragbase + g * 3 + c) * 512 + lane * 8);

    // gate biases (C-init)
    float zb[4];
    #pragma unroll
    for (int g = 0; g < 4; ++g)
        zb[g] = (u < Hn) ? bias[g * Hn + u] : 0.f;
    float cst[4] = {0.f, 0.f, 0.f, 0.f};  // c-state, rows oct*4+r of unit u

    // zero all panel buffers (h0 = c0 = 0, pads)
    for (int idx = tid; idx < 16 * AP_STR; idx += 320) {
        pan1[0][idx] = (f16)0.f; pan1[1][idx] = (f16)0.f;
        pan2[0][idx] = (f16)0.f; pan2[1][idx] = (f16)0.f;
    }
    __syncthreads();   // zero-init before x staging

    // x staging: 160 threads, thread -> (row sr, quad sq), 4 f32 loads -> 4 f16
    const int sr = tid / 10, sq = tid % 10;
    float xv[4] = {0.f, 0.f, 0.f, 0.f};
    if (tid < 160) {
        int t0 = dir ? (T_STEPS - 1) : 0;
        const float* p0 = x + ((size_t)(b0 + sr) * T_STEPS + t0) * DIN;
        union { f16 h[4]; uint2 u; } pk;
        #pragma unroll
        for (int i = 0; i < 4; ++i) { int k = sq * 4 + i; pk.h[i] = (k < DIN) ? (f16)p0[k] : (f16)0.f; }
        *(uint2*)(&pan1[0][sr * AP_STR + sq * 4]) = pk.u;
        int t1 = dir ? (T_STEPS - 2) : 1;
        const float* p1 = x + ((size_t)(b0 + sr) * T_STEPS + t1) * DIN;
        #pragma unroll
        for (int i = 0; i < 4; ++i) { int k = sq * 4 + i; xv[i] = (k < DIN) ? p1[k] : 0.f; }
    }
    __syncthreads();

    const int arow = lm * AP_STR + oct * 8;

    // prologue (L1 waves only): z1(0) -> h1(0) into pan1[1], pan2[1]
    if (!isL2) {
        floatx4 C[4];
        #pragma unroll
        for (int g = 0; g < 4; ++g) C[g] = (floatx4){zb[g], zb[g], zb[g], zb[g]};
        half8 a0 = *(const half8*)(&pan1[0][arow]);
        half8 a1 = *(const half8*)(&pan1[0][arow + 32]);
        half8 a2 = *(const half8*)(&pan1[0][arow + 64]);
        #pragma unroll
        for (int g = 0; g < 4; ++g) {
            C[g] = __builtin_amdgcn_mfma_f32_16x16x32_f16(a0, bf[g][0], C[g], 0, 0, 0);
            C[g] = __builtin_amdgcn_mfma_f32_16x16x32_f16(a1, bf[g][1], C[g], 0, 0, 0);
            C[g] = __builtin_amdgcn_mfma_f32_16x16x32_f16(a2, bf[g][2], C[g], 0, 0, 0);
        }
        #pragma unroll
        for (int r = 0; r < 4; ++r) {
            float cc = sigf(C[2][r] + 1.0f) * cst[r] + sig_tanh(C[0][r], C[1][r]);
            cst[r] = cc;
            float hh = sig_tanh(C[3][r], cc);
            if (u < H1) {
                int row = oct * 4 + r;
                f16 hv = (f16)hh;
                pan1[1][row * AP_STR + 40 + u] = hv;
                pan2[1][row * AP_STR + u] = hv;
            }
        }
    }
    if (tid < 160) {
        union { f16 h[4]; uint2 u; } pk;
        #pragma unroll
        for (int i = 0; i < 4; ++i) pk.h[i] = (f16)xv[i];
        *(uint2*)(&pan1[1][sr * AP_STR + sq * 4]) = pk.u;
        int t2 = dir ? (T_STEPS - 3) : 2;
        const float* p2 = x + ((size_t)(b0 + sr) * T_STEPS + t2) * DIN;
        #pragma unroll
        for (int i = 0; i < 4; ++i) { int k = sq * 4 + i; xv[i] = (k < DIN) ? p2[k] : 0.f; }
    }
    __syncthreads();
    // invariant at iter s: pan1[p]={x(s+1),h1(s)}, pan2[p]={h1(s),h2(s-1)}, xv=x(s+2)
    // L1 waves compute z1(s+1); L2 waves compute z2(s).

    for (int s = 0; s < T_STEPS; ++s) {
        const int p = 1 - (s & 1);

        // issue next x loads early (x(s+3), clamped)
        float xn[4] = {0.f, 0.f, 0.f, 0.f};
        if (tid < 160) {
            int sp = s + 3; if (sp > T_STEPS - 1) sp = T_STEPS - 1;
            int tp = dir ? (T_STEPS - 1 - sp) : sp;
            const float* px = x + ((size_t)(b0 + sr) * T_STEPS + tp) * DIN;
            #pragma unroll
            for (int i = 0; i < 4; ++i) { int k = sq * 4 + i; xn[i] = (k < DIN) ? px[k] : 0.f; }
        }

        // ---- A-fragment LDS reads issued first (latency) ----
        const f16* ap = isL2 ? &pan2[p][0] : &pan1[p][0];
        half8 a0 = *(const half8*)(ap + arow);
        half8 a1 = *(const half8*)(ap + arow + 32);
        half8 a2 = *(const half8*)(ap + arow + 64);

        // ---- stage x(s+2) into pan1[1-p] while the a-reads are in flight ----
        // (writes cols [0,40) of pan1[1-p]; MFMAs read pan[p] only — no conflict)
        if (tid < 160) {
            union { f16 h[4]; uint2 u; } pk;
            #pragma unroll
            for (int i = 0; i < 4; ++i) pk.h[i] = (f16)xv[i];
            *(uint2*)(&pan1[1 - p][sr * AP_STR + sq * 4]) = pk.u;
            #pragma unroll
            for (int i = 0; i < 4; ++i) xv[i] = xn[i];
        }

        // ---- MFMA: each wave does its own unit-group's 4 gate tiles ----
        floatx4 C[4];
        #pragma unroll
        for (int g = 0; g < 4; ++g) C[g] = (floatx4){zb[g], zb[g], zb[g], zb[g]};
        #pragma unroll
        for (int g = 0; g < 4; ++g) {
            C[g] = __builtin_amdgcn_mfma_f32_16x16x32_f16(a0, bf[g][0], C[g], 0, 0, 0);
            C[g] = __builtin_amdgcn_mfma_f32_16x16x32_f16(a1, bf[g][1], C[g], 0, 0, 0);
            C[g] = __builtin_amdgcn_mfma_f32_16x16x32_f16(a2, bf[g][2], C[g], 0, 0, 0);
        }

        // ---- nonlinearity in registers; write h into panels [1-p] ----
        f16* w1 = &pan1[1 - p][0];
        f16* w2 = &pan2[1 - p][0];
        if (!isL2) {
            #pragma unroll
            for (int r = 0; r < 4; ++r) {
                float cc = sigf(C[2][r] + 1.0f) * cst[r] + sig_tanh(C[0][r], C[1][r]);
                cst[r] = cc;
                float hh = sig_tanh(C[3][r], cc);
                if (u < H1) {
                    int row = oct * 4 + r;
                    f16 hv = (f16)hh;
                    w1[row * AP_STR + 40 + u] = hv;   // h1(s+1) for L1 step s+1
                    w2[row * AP_STR + u] = hv;        // h1(s+1) for L2 step s+1
                }
            }
        } else {
            const int t_out = dir ? (T_STEPS - 1 - s) : s;
            #pragma unroll
            for (int r = 0; r < 4; ++r) {
                float dd = sigf(C[2][r] + 1.0f) * cst[r] + sig_tanh(C[0][r], C[1][r]);
                cst[r] = dd;
                float gg = sig_tanh(C[3][r], dd);
                if (u < H2) {
                    int row = oct * 4 + r;
                    f16 gv = (f16)gg;
                    w2[row * AP_STR + 35 + u] = gv;   // h2(s) for L2 step s+1
                    h2s[((size_t)(dir * BATCH + b0 + row) * T_STEPS + t_out) * 32 + u] = gv;
                }
            }
        }

        __syncthreads();   // the single per-step barrier
    }
}

// ---------------- FC stack via MFMA, 64 rows per wave ------------------------------------
// h2s layout [dir][b][t][32]; rid = b*T + t -> reads AND out writes coalesced.
// Software-pipelined: iter t+1's global loads issued before iter t's compute.
__global__ __launch_bounds__(256) void fc_kernel(
    const f16* __restrict__ h2s, const f16* __restrict__ fcp,
    const float* __restrict__ bf1, const float* __restrict__ bf2,
    const float* __restrict__ bo, float* __restrict__ out)
{
    __shared__ f16 apf[4][16 * 72];    // per-wave A panel, stride 72 halfs
    const int tid = threadIdx.x;
    const int wv = tid >> 6, lane = tid & 63;
    const int lm = lane & 15, oct = lane >> 4;
    f16* ap = apf[wv];

    half8 wf[16];
    #pragma unroll
    for (int f = 0; f < 16; ++f)
        wf[f] = *(const half8*)(fcp + (size_t)f * 512 + lane * 8);

    const int ar = lm * 72 + oct * 8;
    const int row = lane >> 2, seg = lane & 3;
    const size_t base = (size_t)blockIdx.x * 256 + wv * 64;

    // prologue: load iter 0's rows
    uint4 vf = *(const uint4*)(h2s + (base + row) * 32 + seg * 8);
    uint4 vb = *(const uint4*)(h2s + ((size_t)BATCH * T_STEPS + base + row) * 32 + seg * 8);

    for (int it = 0; it < 4; ++it) {
        const size_t rid0 = base + it * 16;

        // stage current 16 rows: K = fw h2 [0,30)+pad | bw h2 [32,62)+pad
        *(uint4*)(ap + row * 72 + seg * 8) = vf;
        *(uint4*)(ap + row * 72 + 32 + seg * 8) = vb;

        // issue next iter's loads now; latency hides under fc1/fc2/out
        if (it < 3) {
            const size_t ridn = rid0 + 16;
            vf = *(const uint4*)(h2s + (ridn + row) * 32 + seg * 8);
            vb = *(const uint4*)(h2s + ((size_t)BATCH * T_STEPS + ridn + row) * 32 + seg * 8);
        }

        // fc1: [16x60] @ [60x50] + relu
        {
            half8 a0 = *(const half8*)(ap + ar);
            half8 a1 = *(const half8*)(ap + ar + 32);
            floatx4 C[4];
            #pragma unroll
            for (int t = 0; t < 4; ++t) {
                int col = t * 16 + lm;
                float b = (col < FC1N) ? bf1[col] : 0.f;
                C[t] = (floatx4){b, b, b, b};
                C[t] = __builtin_amdgcn_mfma_f32_16x16x32_f16(a0, wf[t * 2 + 0], C[t], 0, 0, 0);
                C[t] = __builtin_amdgcn_mfma_f32_16x16x32_f16(a1, wf[t * 2 + 1], C[t], 0, 0, 0);
            }
            #pragma unroll
            for (int t = 0; t < 4; ++t) {
                int col = t * 16 + lm;
                #pragma unroll
                for (int r = 0; r < 4; ++r)
                    ap[(oct * 4 + r) * 72 + col] = (f16)fmaxf(C[t][r], 0.f);
            }
        }
        // fc2: [16x50] @ [50x40] + relu
        {
            half8 a0 = *(const half8*)(ap + ar);
            half8 a1 = *(const half8*)(ap + ar + 32);
            floatx4 D[3];
            #pragma unroll
            for (int t = 0; t < 3; ++t) {
                int col = t * 16 + lm;
                float b = (col < FC2N) ? bf2[col] : 0.f;
                D[t] = (floatx4){b, b, b, b};
                D[t] = __builtin_amdgcn_mfma_f32_16x16x32_f16(a0, wf[8 + t * 2 + 0], D[t], 0, 0, 0);
                D[t] = __builtin_amdgcn_mfma_f32_16x16x32_f16(a1, wf[8 + t * 2 + 1], D[t], 0, 0, 0);
            }
            #pragma unroll
            for (int t = 0; t < 3; ++t) {
                int col = t * 16 + lm;
                #pragma unroll
                for (int r = 0; r < 4; ++r)
                    ap[(oct * 4 + r) * 72 + col] = (f16)fmaxf(D[t][r], 0.f);
            }
        }
        // out: [16x40] @ [40x2]
        {
            half8 a0 = *(const half8*)(ap + ar);
            half8 a1 = *(const half8*)(ap + ar + 32);
            float b = (lm < 2) ? bo[lm] : 0.f;
            floatx4 E = (floatx4){b, b, b, b};
            E = __builtin_amdgcn_mfma_f32_16x16x32_f16(a0, wf[14], E, 0, 0, 0);
            E = __builtin_amdgcn_mfma_f32_16x16x32_f16(a1, wf[15], E, 0, 0, 0);
            if (lm < 2) {
                #pragma unroll
                for (int r = 0; r < 4; ++r)
                    out[(rid0 + oct * 4 + r) * 2 + lm] = E[r];
            }
        }
    }
}

extern "C" void kernel_launch(void* const* d_in, const int* in_sizes, int n_in,
                              void* d_out, int out_size, void* d_ws, size_t ws_size,
                              hipStream_t stream) {
    const float* x     = (const float*)d_in[0];
    const float* fw_W1 = (const float*)d_in[1];
    const float* fw_b1 = (const float*)d_in[2];
    const float* fw_W2 = (const float*)d_in[3];
    const float* fw_b2 = (const float*)d_in[4];
    const float* bw_W1 = (const float*)d_in[5];
    const float* bw_b1 = (const float*)d_in[6];
    const float* bw_W2 = (const float*)d_in[7];
    const float* bw_b2 = (const float*)d_in[8];
    const float* Wf1   = (const float*)d_in[9];
    const float* bf1   = (const float*)d_in[10];
    const float* Wf2   = (const float*)d_in[11];
    const float* bf2   = (const float*)d_in[12];
    const float* Wo    = (const float*)d_in[13];
    const float* bo    = (const float*)d_in[14];
    float* outp = (float*)d_out;

    // ws: h2s [2][4096][300][32] f16 | bp 120*512 f16 | fcp 16*512 f16
    f16* h2s = (f16*)d_ws;
    f16* bp  = h2s + (size_t)2 * BATCH * T_STEPS * 32;
    f16* fcp = bp + (size_t)120 * 512;

    wprep_kernel<<<120, 64, 0, stream>>>(fw_W1, bw_W1, fw_W2, bw_W2, bp);
    fcwprep_kernel<<<16, 64, 0, stream>>>(Wf1, Wf2, Wo, fcp);

    dim3 gl(BATCH / 16, 2);   // (256, 2) = 512 blocks -> 2 blocks/CU, 10 waves/CU
    lstm_fused<<<gl, 320, 0, stream>>>(x, bp, fw_b1, bw_b1, fw_b2, bw_b2, h2s);

    fc_kernel<<<(BATCH * T_STEPS) / 256, 256, 0, stream>>>(
        h2s, fcp, bf1, bf2, bo, outp);
}

// Round 5
// 665.902 us; speedup vs baseline: 1.0710x; 1.0710x over previous
//
#include <hip/hip_runtime.h>

// RNN_Model: biLSTM (T=300,B=4096,D=39,H1=35,H2=30) + FC(50,40,2)
// Round 10:
//  lstm: R7 body order (best measured, 452.9) + sig_tanh merged-rcp algebra
//    (kept from R9; VALUBusy 55.5->52.2 measured) + overflow clamp (b<=30,
//    tanh(30)==1.0f exactly -> no numeric change) + running-pointer strength
//    reduction for x prefetch and h2s stores (t moves +-1/step).
//  fc: 64-row batched staging per wave -> 3 layer phases instead of 4x3
//    serial LDS round-trips; 8 global loads in flight; groups pipeline
//    within each phase. __launch_bounds__(256,4), LDS 36.9KB/block.

#define T_STEPS 300
#define DIN 39
#define H1 35
#define H2 30
#define BATCH 4096
#define FC1N 50
#define FC2N 40

#define AP_STR 104       // halfs per A-panel row (52 dwords; rows 16B-aligned for b128)

typedef _Float16 f16;
typedef _Float16 half8 __attribute__((ext_vector_type(8)));
typedef float floatx4 __attribute__((ext_vector_type(4)));

__device__ __forceinline__ float sigf(float x) {
    return __builtin_amdgcn_rcpf(1.0f + __expf(-x));
}
// sig(a)*tanh(b) with a single rcp: (e^{2b}-1) / ((1+e^{-a})(e^{2b}+1)).
// b clamped at 30: tanh(30)==1.0f exactly in f32, and e^60 stays finite
// (avoids inf*0=NaN for pathological c-state growth).
__device__ __forceinline__ float sig_tanh(float a, float b) {
    float bc = fminf(b, 30.0f);
    float ea = __expf(-a);
    float E  = __expf(2.0f * bc);
    return (E - 1.0f) * __builtin_amdgcn_rcpf((1.0f + ea) * (E + 1.0f));
}

// ---------------- wprep: LSTM weight B-fragments, gate-major ----------------------------
// frag = dir*60 + (layer==0 ? ug*12+g*3+c : 36 + ug*12+g*3+c)
// B cols = units ug*16+0..15 of gate g; K rows: L1 x[0,40)|h1[40,75); L2 h1[0,35)|h2[35,65)
__global__ void wprep_kernel(const float* __restrict__ fw1, const float* __restrict__ bw1,
                             const float* __restrict__ fw2, const float* __restrict__ bw2,
                             f16* __restrict__ bp) {
    int frag = blockIdx.x;        // 0..119
    int lane = threadIdx.x;       // 0..63
    int dir = frag / 60;
    int rem = frag % 60;
    int layer = (rem < 36) ? 0 : 1;
    int r2 = (layer == 0) ? rem : rem - 36;
    int ug = r2 / 12, g = (r2 % 12) / 3, c = r2 % 3;
    int u = ug * 16 + (lane & 15);
    const float* W = (layer == 0) ? (dir ? bw1 : fw1) : (dir ? bw2 : fw2);
    for (int j = 0; j < 8; ++j) {
        int k = c * 32 + (lane >> 4) * 8 + j;
        float v = 0.0f;
        if (layer == 0) {
            if (u < H1) {
                int kr = (k < 39) ? k : ((k >= 40 && k < 75) ? k - 1 : -1);
                if (kr >= 0) v = W[kr * (4 * H1) + g * H1 + u];
            }
        } else {
            if (u < H2 && k < 65) v = W[k * (4 * H2) + g * H2 + u];
        }
        bp[(size_t)frag * 512 + lane * 8 + j] = (f16)v;
    }
}

// ---------------- fcwprep: FC weight B-fragments ----------------------------------------
// f 0..7: fc1 (tile 0..3, chunk 0..1); 8..13: fc2 (tile 0..2); 14..15: out
__global__ void fcwprep_kernel(const float* __restrict__ Wf1, const float* __restrict__ Wf2,
                               const float* __restrict__ Wo, f16* __restrict__ fcp) {
    int f = blockIdx.x;
    int lane = threadIdx.x;
    int lm = lane & 15, oct = lane >> 4;
    for (int j = 0; j < 8; ++j) {
        float v = 0.0f;
        if (f < 8) {
            int tile = f >> 1, chunk = f & 1;
            int n = tile * 16 + lm;
            int kl = chunk * 32 + oct * 8 + j;   // LDS K: fw 0..29 | pad | bw 32..61 | pad
            int krow = (kl < 30) ? kl : ((kl >= 32 && kl < 62) ? kl - 2 : -1);
            if (n < FC1N && krow >= 0) v = Wf1[krow * FC1N + n];
        } else if (f < 14) {
            int g = f - 8, tile = g >> 1, chunk = g & 1;
            int n = tile * 16 + lm;
            int k = chunk * 32 + oct * 8 + j;
            if (n < FC2N && k < FC1N) v = Wf2[k * FC2N + n];
        } else {
            int chunk = f - 14;
            int k = chunk * 32 + oct * 8 + j;
            if (lm < 2 && k < FC2N) v = Wo[k * 2 + lm];
        }
        fcp[(size_t)f * 512 + lane * 8 + j] = (f16)v;
    }
}

// ---------------- fused 2-layer LSTM -----------------------------------------------------
__global__ __launch_bounds__(320, 3) void lstm_fused(
    const float* __restrict__ x, const f16* __restrict__ bp,
    const float* __restrict__ fb1, const float* __restrict__ bb1,
    const float* __restrict__ fb2, const float* __restrict__ bb2,
    f16* __restrict__ h2s)
{
    __shared__ f16 pan1[2][16 * AP_STR];  // L1: x[0,40) | h1[40,75) | 0[75,96)
    __shared__ f16 pan2[2][16 * AP_STR];  // L2: h1[0,35) | h2[35,65) | 0[65,96)

    const int tid = threadIdx.x;
    const int b0  = blockIdx.x * 16;
    const int dir = blockIdx.y;
    const int wv   = tid >> 6;            // 0..4
    const int lane = tid & 63;
    const int lm = lane & 15, oct = lane >> 4;
    const bool isL2 = (wv >= 3);
    const int ug = isL2 ? (wv - 3) : wv;  // unit group within its layer
    const int u  = ug * 16 + lm;          // this lane's unit
    const int Hn = isL2 ? H2 : H1;
    const float* bias = isL2 ? (dir ? bb2 : fb2) : (dir ? bb1 : fb1);
    const int fragbase = dir * 60 + (isL2 ? 36 : 0) + ug * 12;

    // persistent gate-major B-fragments (one layer's set per wave)
    half8 bf[4][3];
    #pragma unroll
    for (int g = 0; g < 4; ++g)
        #pragma unroll
        for (int c = 0; c < 3; ++c)
            bf[g][c] = *(const half8*)(bp + (size_t)(fragbase + g * 3 + c) * 512 + lane * 8);

    // gate biases (C-init)
    float zb[4];
    #pragma unroll
    for (int g = 0; g < 4; ++g)
        zb[g] = (u < Hn) ? bias[g * Hn + u] : 0.f;
    float cst[4] = {0.f, 0.f, 0.f, 0.f};  // c-state, rows oct*4+r of unit u

    // running output pointer for L2 waves (t_out moves +-1 per step)
    f16* h2p = h2s + ((size_t)(dir * BATCH + b0 + oct * 4) * T_STEPS
                      + (dir ? (T_STEPS - 1) : 0)) * 32 + u;
    const int h2step = dir ? -32 : 32;

    // zero all panel buffers (h0 = c0 = 0, pads)
    for (int idx = tid; idx < 16 * AP_STR; idx += 320) {
        pan1[0][idx] = (f16)0.f; pan1[1][idx] = (f16)0.f;
        pan2[0][idx] = (f16)0.f; pan2[1][idx] = (f16)0.f;
    }
    __syncthreads();   // zero-init before x staging

    // x staging: 160 threads, thread -> (row sr, quad sq), 4 f32 loads -> 4 f16
    const int sr = tid / 10, sq = tid % 10;
    float xv[4] = {0.f, 0.f, 0.f, 0.f};
    if (tid < 160) {
        int t0 = dir ? (T_STEPS - 1) : 0;
        const float* p0 = x + ((size_t)(b0 + sr) * T_STEPS + t0) * DIN;
        union { f16 h[4]; uint2 u; } pk;
        #pragma unroll
        for (int i = 0; i < 4; ++i) { int k = sq * 4 + i; pk.h[i] = (k < DIN) ? (f16)p0[k] : (f16)0.f; }
        *(uint2*)(&pan1[0][sr * AP_STR + sq * 4]) = pk.u;
        int t1 = dir ? (T_STEPS - 2) : 1;
        const float* p1 = x + ((size_t)(b0 + sr) * T_STEPS + t1) * DIN;
        #pragma unroll
        for (int i = 0; i < 4; ++i) { int k = sq * 4 + i; xv[i] = (k < DIN) ? p1[k] : 0.f; }
    }
    __syncthreads();

    const int arow = lm * AP_STR + oct * 8;

    // prologue (L1 waves only): z1(0) -> h1(0) into pan1[1], pan2[1]
    if (!isL2) {
        floatx4 C[4];
        #pragma unroll
        for (int g = 0; g < 4; ++g) C[g] = (floatx4){zb[g], zb[g], zb[g], zb[g]};
        half8 a0 = *(const half8*)(&pan1[0][arow]);
        half8 a1 = *(const half8*)(&pan1[0][arow + 32]);
        half8 a2 = *(const half8*)(&pan1[0][arow + 64]);
        #pragma unroll
        for (int g = 0; g < 4; ++g) {
            C[g] = __builtin_amdgcn_mfma_f32_16x16x32_f16(a0, bf[g][0], C[g], 0, 0, 0);
            C[g] = __builtin_amdgcn_mfma_f32_16x16x32_f16(a1, bf[g][1], C[g], 0, 0, 0);
            C[g] = __builtin_amdgcn_mfma_f32_16x16x32_f16(a2, bf[g][2], C[g], 0, 0, 0);
        }
        #pragma unroll
        for (int r = 0; r < 4; ++r) {
            float cc = sigf(C[2][r] + 1.0f) * cst[r] + sig_tanh(C[0][r], C[1][r]);
            cst[r] = cc;
            float hh = sig_tanh(C[3][r], cc);
            if (u < H1) {
                int row = oct * 4 + r;
                f16 hv = (f16)hh;
                pan1[1][row * AP_STR + 40 + u] = hv;
                pan2[1][row * AP_STR + u] = hv;
            }
        }
    }
    // x prefetch running pointer: first in-loop load target is t(s=0,+3)
    const float* px = x + ((size_t)(b0 + sr) * T_STEPS
                           + (dir ? (T_STEPS - 4) : 3)) * DIN + sq * 4;
    const int xstep = dir ? -DIN : DIN;
    if (tid < 160) {
        union { f16 h[4]; uint2 u; } pk;
        #pragma unroll
        for (int i = 0; i < 4; ++i) pk.h[i] = (f16)xv[i];
        *(uint2*)(&pan1[1][sr * AP_STR + sq * 4]) = pk.u;
        int t2 = dir ? (T_STEPS - 3) : 2;
        const float* p2 = x + ((size_t)(b0 + sr) * T_STEPS + t2) * DIN;
        #pragma unroll
        for (int i = 0; i < 4; ++i) { int k = sq * 4 + i; xv[i] = (k < DIN) ? p2[k] : 0.f; }
    }
    __syncthreads();
    // invariant at iter s: pan1[p]={x(s+1),h1(s)}, pan2[p]={h1(s),h2(s-1)}, xv=x(s+2)
    // L1 waves compute z1(s+1); L2 waves compute z2(s).

    for (int s = 0; s < T_STEPS; ++s) {
        const int p = 1 - (s & 1);

        // issue next x loads early (x(s+3); px clamps at the last row)
        float xn[4] = {0.f, 0.f, 0.f, 0.f};
        if (tid < 160) {
            #pragma unroll
            for (int i = 0; i < 4; ++i) { int k = sq * 4 + i; xn[i] = (k < DIN) ? px[i] : 0.f; }
        }
        if (s < T_STEPS - 4) px += xstep;   // stop advancing once clamped

        // ---- MFMA: each wave does its own unit-group's 4 gate tiles ----
        const f16* ap = isL2 ? &pan2[p][0] : &pan1[p][0];
        floatx4 C[4];
        #pragma unroll
        for (int g = 0; g < 4; ++g) C[g] = (floatx4){zb[g], zb[g], zb[g], zb[g]};
        {
            half8 a0 = *(const half8*)(ap + arow);
            half8 a1 = *(const half8*)(ap + arow + 32);
            half8 a2 = *(const half8*)(ap + arow + 64);
            #pragma unroll
            for (int g = 0; g < 4; ++g) {
                C[g] = __builtin_amdgcn_mfma_f32_16x16x32_f16(a0, bf[g][0], C[g], 0, 0, 0);
                C[g] = __builtin_amdgcn_mfma_f32_16x16x32_f16(a1, bf[g][1], C[g], 0, 0, 0);
                C[g] = __builtin_amdgcn_mfma_f32_16x16x32_f16(a2, bf[g][2], C[g], 0, 0, 0);
            }
        }

        // ---- nonlinearity in registers; write h into panels [1-p] ----
        f16* w1 = &pan1[1 - p][0];
        f16* w2 = &pan2[1 - p][0];
        if (!isL2) {
            #pragma unroll
            for (int r = 0; r < 4; ++r) {
                float cc = sigf(C[2][r] + 1.0f) * cst[r] + sig_tanh(C[0][r], C[1][r]);
                cst[r] = cc;
                float hh = sig_tanh(C[3][r], cc);
                if (u < H1) {
                    int row = oct * 4 + r;
                    f16 hv = (f16)hh;
                    w1[row * AP_STR + 40 + u] = hv;   // h1(s+1) for L1 step s+1
                    w2[row * AP_STR + u] = hv;        // h1(s+1) for L2 step s+1
                }
            }
        } else {
            #pragma unroll
            for (int r = 0; r < 4; ++r) {
                float dd = sigf(C[2][r] + 1.0f) * cst[r] + sig_tanh(C[0][r], C[1][r]);
                cst[r] = dd;
                float gg = sig_tanh(C[3][r], dd);
                if (u < H2) {
                    int row = oct * 4 + r;
                    f16 gv = (f16)gg;
                    w2[row * AP_STR + 35 + u] = gv;          // h2(s) for L2 step s+1
                    h2p[(size_t)r * T_STEPS * 32] = gv;      // h2s out (running ptr)
                }
            }
        }
        h2p += h2step;

        // ---- stage x(s+2) into pan1[1-p] ----
        if (tid < 160) {
            union { f16 h[4]; uint2 u; } pk;
            #pragma unroll
            for (int i = 0; i < 4; ++i) pk.h[i] = (f16)xv[i];
            *(uint2*)(&pan1[1 - p][sr * AP_STR + sq * 4]) = pk.u;
            #pragma unroll
            for (int i = 0; i < 4; ++i) xv[i] = xn[i];
        }
        __syncthreads();   // the single per-step barrier
    }
}

// ---------------- FC stack via MFMA, 64 rows per wave, layer-phased ----------------------
// h2s layout [dir][b][t][32]; rid = b*T + t -> reads AND out writes coalesced.
// Stage all 64 rows (8 loads in flight), then fc1 x4 groups, fc2 x4, out x4:
// 3 LDS round-trip phases per wave instead of 12; groups pipeline in-phase.
__global__ __launch_bounds__(256, 4) void fc_kernel(
    const f16* __restrict__ h2s, const f16* __restrict__ fcp,
    const float* __restrict__ bf1, const float* __restrict__ bf2,
    const float* __restrict__ bo, float* __restrict__ out)
{
    __shared__ f16 apf[4][64 * 72];    // per-wave 64-row A panel, stride 72 halfs
    const int tid = threadIdx.x;
    const int wv = tid >> 6, lane = tid & 63;
    const int lm = lane & 15, oct = lane >> 4;
    f16* ap = apf[wv];

    half8 wf[16];
    #pragma unroll
    for (int f = 0; f < 16; ++f)
        wf[f] = *(const half8*)(fcp + (size_t)f * 512 + lane * 8);

    const int ar = lm * 72 + oct * 8;
    const int row = lane >> 2, seg = lane & 3;
    const size_t base = (size_t)blockIdx.x * 256 + wv * 64;

    // ---- stage 64 rows: K = fw h2 [0,30)+pad | bw h2 [32,62)+pad ----
    uint4 vf[4], vb[4];
    #pragma unroll
    for (int g = 0; g < 4; ++g) {
        const size_t r0 = base + g * 16 + row;
        vf[g] = *(const uint4*)(h2s + r0 * 32 + seg * 8);
        vb[g] = *(const uint4*)(h2s + ((size_t)BATCH * T_STEPS + r0) * 32 + seg * 8);
    }
    #pragma unroll
    for (int g = 0; g < 4; ++g) {
        *(uint4*)(ap + (g * 16 + row) * 72 + seg * 8) = vf[g];
        *(uint4*)(ap + (g * 16 + row) * 72 + 32 + seg * 8) = vb[g];
    }

    // ---- fc1: [16x60] @ [60x50] + relu, all 4 groups ----
    #pragma unroll
    for (int g = 0; g < 4; ++g) {
        f16* agp = ap + g * 16 * 72;
        half8 a0 = *(const half8*)(agp + ar);
        half8 a1 = *(const half8*)(agp + ar + 32);
        floatx4 C[4];
        #pragma unroll
        for (int t = 0; t < 4; ++t) {
            int col = t * 16 + lm;
            float b = (col < FC1N) ? bf1[col] : 0.f;
            C[t] = (floatx4){b, b, b, b};
            C[t] = __builtin_amdgcn_mfma_f32_16x16x32_f16(a0, wf[t * 2 + 0], C[t], 0, 0, 0);
            C[t] = __builtin_amdgcn_mfma_f32_16x16x32_f16(a1, wf[t * 2 + 1], C[t], 0, 0, 0);
        }
        #pragma unroll
        for (int t = 0; t < 4; ++t) {
            int col = t * 16 + lm;
            #pragma unroll
            for (int r = 0; r < 4; ++r)
                agp[(oct * 4 + r) * 72 + col] = (f16)fmaxf(C[t][r], 0.f);
        }
    }

    // ---- fc2: [16x50] @ [50x40] + relu, all 4 groups ----
    #pragma unroll
    for (int g = 0; g < 4; ++g) {
        f16* agp = ap + g * 16 * 72;
        half8 a0 = *(const half8*)(agp + ar);
        half8 a1 = *(const half8*)(agp + ar + 32);
        floatx4 D[3];
        #pragma unroll
        for (int t = 0; t < 3; ++t) {
            int col = t * 16 + lm;
            float b = (col < FC2N) ? bf2[col] : 0.f;
            D[t] = (floatx4){b, b, b, b};
            D[t] = __builtin_amdgcn_mfma_f32_16x16x32_f16(a0, wf[8 + t * 2 + 0], D[t], 0, 0, 0);
            D[t] = __builtin_amdgcn_mfma_f32_16x16x32_f16(a1, wf[8 + t * 2 + 1], D[t], 0, 0, 0);
        }
        #pragma unroll
        for (int t = 0; t < 3; ++t) {
            int col = t * 16 + lm;
            #pragma unroll
            for (int r = 0; r < 4; ++r)
                agp[(oct * 4 + r) * 72 + col] = (f16)fmaxf(D[t][r], 0.f);
        }
    }

    // ---- out: [16x40] @ [40x2], all 4 groups ----
    #pragma unroll
    for (int g = 0; g < 4; ++g) {
        f16* agp = ap + g * 16 * 72;
        half8 a0 = *(const half8*)(agp + ar);
        half8 a1 = *(const half8*)(agp + ar + 32);
        float b = (lm < 2) ? bo[lm] : 0.f;
        floatx4 E = (floatx4){b, b, b, b};
        E = __builtin_amdgcn_mfma_f32_16x16x32_f16(a0, wf[14], E, 0, 0, 0);
        E = __builtin_amdgcn_mfma_f32_16x16x32_f16(a1, wf[15], E, 0, 0, 0);
        if (lm < 2) {
            const size_t rid0 = base + g * 16;
            #pragma unroll
            for (int r = 0; r < 4; ++r)
                out[(rid0 + oct * 4 + r) * 2 + lm] = E[r];
        }
    }
}

extern "C" void kernel_launch(void* const* d_in, const int* in_sizes, int n_in,
                              void* d_out, int out_size, void* d_ws, size_t ws_size,
                              hipStream_t stream) {
    const float* x     = (const float*)d_in[0];
    const float* fw_W1 = (const float*)d_in[1];
    const float* fw_b1 = (const float*)d_in[2];
    const float* fw_W2 = (const float*)d_in[3];
    const float* fw_b2 = (const float*)d_in[4];
    const float* bw_W1 = (const float*)d_in[5];
    const float* bw_b1 = (const float*)d_in[6];
    const float* bw_W2 = (const float*)d_in[7];
    const float* bw_b2 = (const float*)d_in[8];
    const float* Wf1   = (const float*)d_in[9];
    const float* bf1   = (const float*)d_in[10];
    const float* Wf2   = (const float*)d_in[11];
    const float* bf2   = (const float*)d_in[12];
    const float* Wo    = (const float*)d_in[13];
    const float* bo    = (const float*)d_in[14];
    float* outp = (float*)d_out;

    // ws: h2s [2][4096][300][32] f16 | bp 120*512 f16 | fcp 16*512 f16
    f16* h2s = (f16*)d_ws;
    f16* bp  = h2s + (size_t)2 * BATCH * T_STEPS * 32;
    f16* fcp = bp + (size_t)120 * 512;

    wprep_kernel<<<120, 64, 0, stream>>>(fw_W1, bw_W1, fw_W2, bw_W2, bp);
    fcwprep_kernel<<<16, 64, 0, stream>>>(Wf1, Wf2, Wo, fcp);

    dim3 gl(BATCH / 16, 2);   // (256, 2) = 512 blocks -> 2 blocks/CU, 10 waves/CU
    lstm_fused<<<gl, 320, 0, stream>>>(x, bp, fw_b1, bw_b1, fw_b2, bw_b2, h2s);

    fc_kernel<<<(BATCH * T_STEPS) / 256, 256, 0, stream>>>(
        h2s, fcp, bf1, bf2, bo, outp);
}